// Round 13
// baseline (108.422 us; speedup 1.0000x reference)
//
#include <hip/hip_runtime.h>
#include <stdint.h>

// DigitCaps with O=1: routing softmax over one out-capsule is identity, so
// the reference reduces to
//   s[b,v]  = sum_{i,d} W[i,v,d] * x[b,i,d]        (M=32, N=512, K=32768 GEMM)
//   out     = s * sqrt(sq)/(1+sq),  sq = sum_v s^2  (per-b squash)
// Both tuple outputs (t, outputs) are identical [32,1,512] tensors.
//
// R13: caps_mfma's rolling K-loop capped memory-level parallelism (compiler
// waits on each unroll-group's loads before issuing the next; ~6% duty/wave,
// ~4 TB/s). Fix: ONE kstep per wave, straight-line code - 1024-thr blocks,
// 16 waves, each wave: 4 VMEM issued together, 1 wait, 2 MFMAs, 16-wave LDS
// k-reduce. 32 waves/CU x 4 KB in flight >> Little's-law need -> W stream at
// near-memcpy BW. Fixed harness floor: ~83us of 0xAA workspace fills.

#define NB 32
#define NI 4096
#define NV 512
#define ND 8
#define NK 32768            // K = NI*ND
#define KB 128              // k-blocks (partial slices)
#define KSB (NK / KB)       // 256 k per block
#define KSW 16              // 16 k per wave = one 32x32x16 MFMA step
#define NG (KB / 8)         // 16 second-stage groups

typedef __fp16 f16x8 __attribute__((ext_vector_type(8)));
typedef __fp16 f16x2 __attribute__((ext_vector_type(2)));
typedef float  f32x16 __attribute__((ext_vector_type(16)));

// ---------------------------------------------------------------------------
// Kernel 1: split x (fp32 [32][32768]) into f16 hi/lo planes in FRAGMENT
// order: xt[(g*32 + b)*8 + j] where g=k>>3, j=k&7. hi = rtz(x); lo = x - hi.
// ---------------------------------------------------------------------------
__global__ __launch_bounds__(256) void x_prep(
    const float* __restrict__ x, __fp16* __restrict__ xh,
    __fp16* __restrict__ xl)
{
    const int tid = blockIdx.x * 256 + threadIdx.x;   // 131072 total
    const int b = tid & 31;
    const int g = tid >> 5;

    const float4* xp = (const float4*)(x + (size_t)b * NK + (size_t)g * 8);
    const float4 f0 = xp[0];
    const float4 f1 = xp[1];

    const f16x2 h0 = __builtin_amdgcn_cvt_pkrtz(f0.x, f0.y);
    const f16x2 h1 = __builtin_amdgcn_cvt_pkrtz(f0.z, f0.w);
    const f16x2 h2 = __builtin_amdgcn_cvt_pkrtz(f1.x, f1.y);
    const f16x2 h3 = __builtin_amdgcn_cvt_pkrtz(f1.z, f1.w);
    const f16x2 l0 = __builtin_amdgcn_cvt_pkrtz(f0.x - (float)h0.x, f0.y - (float)h0.y);
    const f16x2 l1 = __builtin_amdgcn_cvt_pkrtz(f0.z - (float)h1.x, f0.w - (float)h1.y);
    const f16x2 l2 = __builtin_amdgcn_cvt_pkrtz(f1.x - (float)h2.x, f1.y - (float)h2.y);
    const f16x2 l3 = __builtin_amdgcn_cvt_pkrtz(f1.z - (float)h3.x, f1.w - (float)h3.y);

    const f16x8 h = {h0.x, h0.y, h1.x, h1.y, h2.x, h2.y, h3.x, h3.y};
    const f16x8 l = {l0.x, l0.y, l1.x, l1.y, l2.x, l2.y, l3.x, l3.y};
    ((f16x8*)xh)[tid] = h;
    ((f16x8*)xl)[tid] = l;
}

// ---------------------------------------------------------------------------
// Kernel 2: partial_h[kb][b][v] (f16) = sum over 256-k slice of x*W.
// Grid: kb(128) x vg(16) = 2048 blocks of 1024 threads (16 waves).
// Wave w owns k = kb*256 + w*16 .. +15: STRAIGHT-LINE body, 4 VMEM in
// flight (2 W float4 + 2 a-frag f16x8), one wait, 2 MFMAs (x hi + x lo).
// Epilogue: 16-wave LDS k-reduce -> one f16 32x32 tile per block.
// kb fastest in blockIdx: the 16 vg-siblings sharing an x-slice differ by
// 128 in id -> same XCD (x planes L2-resident).
// ---------------------------------------------------------------------------
__global__ __launch_bounds__(1024) void caps_mfma(
    const float* __restrict__ W, const __fp16* __restrict__ xh,
    const __fp16* __restrict__ xl, __fp16* __restrict__ partial_h)
{
    const int t    = threadIdx.x;
    const int lane = t & 63;
    const int wave = t >> 6;       // 0..15
    const int half = lane >> 5;    // 0/1: which 8-k group of the 16-k step
    const int ln32 = lane & 31;

    const int kb = blockIdx.x & (KB - 1);
    const int vg = blockIdx.x >> 7;
    const int v0 = vg * 32;
    const int k0 = kb * KSB + wave * KSW;
    const int g0 = (k0 >> 3) + half;   // W row / k-group for this lane

    const __fp16* ah = xh + ((size_t)g0 * 32 + ln32) * 8;
    const __fp16* al = xl + ((size_t)g0 * 32 + ln32) * 8;
    const float4* wp = (const float4*)(W + ((size_t)g0 * NV + v0 + ln32) * ND);

    // all 4 VMEM issue back-to-back; single wait before the cvt/MFMA
    const float4 w0 = wp[0];
    const float4 w1 = wp[1];
    const f16x8 a_hi = *(const f16x8*)ah;
    const f16x8 a_lo = *(const f16x8*)al;

    const f16x2 h01 = __builtin_amdgcn_cvt_pkrtz(w0.x, w0.y);
    const f16x2 h23 = __builtin_amdgcn_cvt_pkrtz(w0.z, w0.w);
    const f16x2 h45 = __builtin_amdgcn_cvt_pkrtz(w1.x, w1.y);
    const f16x2 h67 = __builtin_amdgcn_cvt_pkrtz(w1.z, w1.w);
    const f16x8 b = {h01.x, h01.y, h23.x, h23.y, h45.x, h45.y, h67.x, h67.y};

    f32x16 acc;
#pragma unroll
    for (int r = 0; r < 16; ++r) acc[r] = 0.0f;
    acc = __builtin_amdgcn_mfma_f32_32x32x16_f16(a_hi, b, acc, 0, 0, 0);
    acc = __builtin_amdgcn_mfma_f32_32x32x16_f16(a_lo, b, acc, 0, 0, 0);

    // 16-wave k-reduce via LDS: wave w writes its 32x32 f32 tile, then
    // thread t sums element t across the 16 tiles and stores f16.
    __shared__ float red[16 * 1024];   // 64 KB -> 2 blocks/CU
#pragma unroll
    for (int r = 0; r < 16; ++r)
        red[wave * 1024 + r * 64 + lane] = acc[r];
    __syncthreads();

    float val = 0.0f;
#pragma unroll
    for (int w = 0; w < 16; ++w)       // 16 independent LDS reads
        val += red[w * 1024 + t];

    const int r  = t >> 6;
    const int ln = t & 63;
    // C/D layout (m74/m101): col = lane&31 (v), row = (reg&3)+8*(reg>>2)+4*(lane>>5) (b)
    const int row = (r & 3) + 8 * (r >> 2) + 4 * (ln >> 5);
    const int col = ln & 31;
    partial_h[((size_t)kb * NB + row) * NV + v0 + col] = (__fp16)val;
}

// ---------------------------------------------------------------------------
// Kernel 3: tree reduce 8 kb-slices -> 1 (f16 in, f32 out).
// Grid: NG(16) x NB(32) = 512 blocks, 256 threads; thread t owns v-pair t.
// ---------------------------------------------------------------------------
__global__ __launch_bounds__(256) void caps_reduce8(
    const __fp16* __restrict__ partial_h, float* __restrict__ partial2)
{
    const int t = threadIdx.x;             // v-pair index (v = 2t, 2t+1)
    const int b = blockIdx.x & 31;
    const int g = blockIdx.x >> 5;         // 0..NG-1

    const __fp16* p = partial_h + ((size_t)(g * 8) * NB + b) * NV + 2 * t;
    float s0 = 0.0f, s1 = 0.0f;
#pragma unroll
    for (int j = 0; j < 8; ++j) {
        const f16x2 h = *(const f16x2*)(p + (size_t)j * NB * NV);
        s0 += (float)h.x;
        s1 += (float)h.y;
    }

    float2 o = {s0, s1};
    ((float2*)(partial2 + ((size_t)g * NB + b) * NV))[t] = o;
}

// ---------------------------------------------------------------------------
// Kernel 4: final reduce over NG groups + squash + write both outputs.
// Grid: 32 blocks (one per b) x 512 threads (one per v). Reads 1 MB.
// ---------------------------------------------------------------------------
__global__ __launch_bounds__(512) void caps_finish(
    const float* __restrict__ partial2, float* __restrict__ out)
{
    const int v = threadIdx.x;
    const int b = blockIdx.x;

    float s = 0.0f;
#pragma unroll
    for (int g = 0; g < NG; ++g)         // 16 independent coalesced loads
        s += partial2[((size_t)g * NB + b) * NV + v];

    float sq = s * s;
#pragma unroll
    for (int off = 32; off > 0; off >>= 1)
        sq += __shfl_xor(sq, off, 64);

    __shared__ float red[8];
    if ((v & 63) == 0) red[v >> 6] = sq;
    __syncthreads();
    float tot = 0.0f;
#pragma unroll
    for (int wv = 0; wv < 8; ++wv) tot += red[wv];

    // squash factor: sq/((1+sq)*sqrt(sq)) == sqrt(sq)/(1+sq)
    const float factor = sqrtf(tot) / (1.0f + tot);
    const float r = s * factor;

    out[(size_t)b * NV + v]           = r;  // output 0: t       [B,1,V]
    out[NB * NV + (size_t)b * NV + v] = r;  // output 1: outputs [B,O,V]
}

extern "C" void kernel_launch(void* const* d_in, const int* in_sizes, int n_in,
                              void* d_out, int out_size, void* d_ws, size_t ws_size,
                              hipStream_t stream) {
    const float* x = (const float*)d_in[0];   // [32, 4096, 8]
    const float* W = (const float*)d_in[1];   // [1, 4096, 512, 8]
    float* out     = (float*)d_out;           // 2 x [32,1,512] concatenated

    __fp16* xh       = (__fp16*)d_ws;                         // 2 MB
    __fp16* xl       = xh + (size_t)NB * NK;                  // 2 MB
    __fp16* partialh = xl + (size_t)NB * NK;                  // 4 MB (f16)
    float*  partial2 = (float*)(partialh + (size_t)KB * NB * NV);  // 1 MB

    x_prep<<<(NB * NK / 8) / 256, 256, 0, stream>>>(x, xh, xl);
    caps_mfma<<<KB * 16, 1024, 0, stream>>>(W, xh, xl, partialh);
    caps_reduce8<<<NG * NB, 256, 0, stream>>>(partialh, partial2);
    caps_finish<<<NB, 512, 0, stream>>>(partial2, out);
}

// Round 14
// 105.389 us; speedup vs baseline: 1.0288x; 1.0288x over previous
//
#include <hip/hip_runtime.h>
#include <stdint.h>

// DigitCaps with O=1: routing softmax over one out-capsule is identity, so
// the reference reduces to
//   s[b,v]  = sum_{i,d} W[i,v,d] * x[b,i,d]        (M=32, N=512, K=32768 GEMM)
//   out     = s * sqrt(sq)/(1+sq),  sq = sum_v s^2  (per-b squash)
// Both tuple outputs (t, outputs) are identical [32,1,512] tensors.
//
// R14: R13 (max TLP) was neutral -> caps_mfma is AT its HBM stream floor
// (~11-12us for 64 MB of W). Remaining fat is overhead: LDS k-reduce
// epilogue traffic (256 MB across the grid) and a 4-kernel chain. Changes:
// KSW 16->32 (2 straight-line ksteps/wave, 8 VMEM in flight) -> KB=64,
// halving LDS epilogue traffic; drop reduce8 (finish reads the 2 MB f16
// partials directly). Fixed harness floor: ~83us of 0xAA workspace fills.

#define NB 32
#define NI 4096
#define NV 512
#define ND 8
#define NK 32768            // K = NI*ND
#define KB 64               // k-blocks (partial slices)
#define KSB (NK / KB)       // 512 k per block (16 waves x 32)
#define KSW 32              // 32 k per wave = two 32x32x16 MFMA steps

typedef __fp16 f16x8 __attribute__((ext_vector_type(8)));
typedef __fp16 f16x2 __attribute__((ext_vector_type(2)));
typedef float  f32x16 __attribute__((ext_vector_type(16)));

// ---------------------------------------------------------------------------
// Kernel 1: split x (fp32 [32][32768]) into f16 hi/lo planes in FRAGMENT
// order: xt[(g*32 + b)*8 + j] where g=k>>3, j=k&7. hi = rtz(x); lo = x - hi.
// ---------------------------------------------------------------------------
__global__ __launch_bounds__(256) void x_prep(
    const float* __restrict__ x, __fp16* __restrict__ xh,
    __fp16* __restrict__ xl)
{
    const int tid = blockIdx.x * 256 + threadIdx.x;   // 131072 total
    const int b = tid & 31;
    const int g = tid >> 5;

    const float4* xp = (const float4*)(x + (size_t)b * NK + (size_t)g * 8);
    const float4 f0 = xp[0];
    const float4 f1 = xp[1];

    const f16x2 h0 = __builtin_amdgcn_cvt_pkrtz(f0.x, f0.y);
    const f16x2 h1 = __builtin_amdgcn_cvt_pkrtz(f0.z, f0.w);
    const f16x2 h2 = __builtin_amdgcn_cvt_pkrtz(f1.x, f1.y);
    const f16x2 h3 = __builtin_amdgcn_cvt_pkrtz(f1.z, f1.w);
    const f16x2 l0 = __builtin_amdgcn_cvt_pkrtz(f0.x - (float)h0.x, f0.y - (float)h0.y);
    const f16x2 l1 = __builtin_amdgcn_cvt_pkrtz(f0.z - (float)h1.x, f0.w - (float)h1.y);
    const f16x2 l2 = __builtin_amdgcn_cvt_pkrtz(f1.x - (float)h2.x, f1.y - (float)h2.y);
    const f16x2 l3 = __builtin_amdgcn_cvt_pkrtz(f1.z - (float)h3.x, f1.w - (float)h3.y);

    const f16x8 h = {h0.x, h0.y, h1.x, h1.y, h2.x, h2.y, h3.x, h3.y};
    const f16x8 l = {l0.x, l0.y, l1.x, l1.y, l2.x, l2.y, l3.x, l3.y};
    ((f16x8*)xh)[tid] = h;
    ((f16x8*)xl)[tid] = l;
}

// ---------------------------------------------------------------------------
// Kernel 2: partial_h[kb][b][v] (f16) = sum over 512-k slice of x*W.
// Grid: kb(64) x vg(16) = 1024 blocks of 1024 threads (16 waves).
// Wave w owns k = kb*512 + w*32 .. +31: straight-line 2 ksteps, 8 VMEM
// (4 W float4 + 4 a-frag f16x8) issued together, 4 MFMAs (hi+lo per kstep).
// Epilogue: 16-wave LDS k-reduce -> one f16 32x32 tile per block.
// kb fastest in blockIdx: the 16 vg-siblings sharing an x-slice differ by
// 64 in id -> co-XCD-ish under round-robin (x planes L2/L3-resident anyway).
// ---------------------------------------------------------------------------
__global__ __launch_bounds__(1024) void caps_mfma(
    const float* __restrict__ W, const __fp16* __restrict__ xh,
    const __fp16* __restrict__ xl, __fp16* __restrict__ partial_h)
{
    const int t    = threadIdx.x;
    const int lane = t & 63;
    const int wave = t >> 6;       // 0..15
    const int half = lane >> 5;    // 0/1: which 8-k group of a 16-k step
    const int ln32 = lane & 31;

    const int kb = blockIdx.x & (KB - 1);
    const int vg = blockIdx.x >> 6;
    const int v0 = vg * 32;
    const int k0 = kb * KSB + wave * KSW;
    const int g0 = (k0 >> 3) + half;     // k-group for kstep 0
    const int g1 = g0 + 2;               // k-group for kstep 1

    const __fp16* ah0 = xh + ((size_t)g0 * 32 + ln32) * 8;
    const __fp16* al0 = xl + ((size_t)g0 * 32 + ln32) * 8;
    const float4* wp0 = (const float4*)(W + ((size_t)g0 * NV + v0 + ln32) * ND);
    const __fp16* ah1 = xh + ((size_t)g1 * 32 + ln32) * 8;
    const __fp16* al1 = xl + ((size_t)g1 * 32 + ln32) * 8;
    const float4* wp1 = (const float4*)(W + ((size_t)g1 * NV + v0 + ln32) * ND);

    // 8 VMEM issue back-to-back (straight-line, no loop to sink across)
    const float4 w00 = wp0[0];
    const float4 w01 = wp0[1];
    const float4 w10 = wp1[0];
    const float4 w11 = wp1[1];
    const f16x8 a0h = *(const f16x8*)ah0;
    const f16x8 a0l = *(const f16x8*)al0;
    const f16x8 a1h = *(const f16x8*)ah1;
    const f16x8 a1l = *(const f16x8*)al1;

    const f16x2 p01 = __builtin_amdgcn_cvt_pkrtz(w00.x, w00.y);
    const f16x2 p23 = __builtin_amdgcn_cvt_pkrtz(w00.z, w00.w);
    const f16x2 p45 = __builtin_amdgcn_cvt_pkrtz(w01.x, w01.y);
    const f16x2 p67 = __builtin_amdgcn_cvt_pkrtz(w01.z, w01.w);
    const f16x8 b0 = {p01.x, p01.y, p23.x, p23.y, p45.x, p45.y, p67.x, p67.y};
    const f16x2 q01 = __builtin_amdgcn_cvt_pkrtz(w10.x, w10.y);
    const f16x2 q23 = __builtin_amdgcn_cvt_pkrtz(w10.z, w10.w);
    const f16x2 q45 = __builtin_amdgcn_cvt_pkrtz(w11.x, w11.y);
    const f16x2 q67 = __builtin_amdgcn_cvt_pkrtz(w11.z, w11.w);
    const f16x8 b1 = {q01.x, q01.y, q23.x, q23.y, q45.x, q45.y, q67.x, q67.y};

    f32x16 acc;
#pragma unroll
    for (int r = 0; r < 16; ++r) acc[r] = 0.0f;
    acc = __builtin_amdgcn_mfma_f32_32x32x16_f16(a0h, b0, acc, 0, 0, 0);
    acc = __builtin_amdgcn_mfma_f32_32x32x16_f16(a0l, b0, acc, 0, 0, 0);
    acc = __builtin_amdgcn_mfma_f32_32x32x16_f16(a1h, b1, acc, 0, 0, 0);
    acc = __builtin_amdgcn_mfma_f32_32x32x16_f16(a1l, b1, acc, 0, 0, 0);

    // 16-wave k-reduce via LDS: wave w writes its 32x32 f32 tile, then
    // thread t sums element t across the 16 tiles and stores f16.
    __shared__ float red[16 * 1024];   // 64 KB
#pragma unroll
    for (int r = 0; r < 16; ++r)
        red[wave * 1024 + r * 64 + lane] = acc[r];
    __syncthreads();

    float val = 0.0f;
#pragma unroll
    for (int w = 0; w < 16; ++w)       // 16 independent LDS reads
        val += red[w * 1024 + t];

    const int r  = t >> 6;
    const int ln = t & 63;
    // C/D layout (m74/m101): col = lane&31 (v), row = (reg&3)+8*(reg>>2)+4*(lane>>5) (b)
    const int row = (r & 3) + 8 * (r >> 2) + 4 * (ln >> 5);
    const int col = ln & 31;
    partial_h[((size_t)kb * NB + row) * NV + v0 + col] = (__fp16)val;
}

// ---------------------------------------------------------------------------
// Kernel 3: reduce KB f16 slices + squash + write both outputs.
// Grid: 32 blocks (one per b) x 1024 threads. Thread t: v = t&511,
// kb-half = t>>9 (32 slices each) -> 2-way MLP; LDS combine; squash.
// ---------------------------------------------------------------------------
__global__ __launch_bounds__(1024) void caps_finish(
    const __fp16* __restrict__ partial_h, float* __restrict__ out)
{
    const int t = threadIdx.x;
    const int v = t & 511;
    const int h = t >> 9;              // 0/1: which half of the kb range
    const int b = blockIdx.x;

    float s = 0.0f;
#pragma unroll
    for (int g = 0; g < KB / 2; ++g)   // 32 independent coalesced loads
        s += (float)partial_h[((size_t)(h * (KB / 2) + g) * NB + b) * NV + v];

    __shared__ float sv[1024];
    sv[t] = s;
    __syncthreads();

    float sq = 0.0f;
    float stot = 0.0f;
    if (t < 512) {
        stot = sv[t] + sv[t + 512];
        sq = stot * stot;
    }
#pragma unroll
    for (int off = 32; off > 0; off >>= 1)
        sq += __shfl_xor(sq, off, 64);

    __shared__ float red[16];
    if ((t & 63) == 0) red[t >> 6] = sq;
    __syncthreads();
    if (t < 512) {
        float tot = 0.0f;
#pragma unroll
        for (int wv = 0; wv < 8; ++wv) tot += red[wv];   // waves 8..15 hold sq=0 dup of 0..7? no:
        // threads 512..1023 (waves 8..15) computed sq=0 -> their red entries are 0; sum all 16 is safe
#pragma unroll
        for (int wv = 8; wv < 16; ++wv) tot += red[wv];

        // squash factor: sq/((1+sq)*sqrt(sq)) == sqrt(sq)/(1+sq)
        const float factor = sqrtf(tot) / (1.0f + tot);
        const float r = stot * factor;

        out[(size_t)b * NV + v]           = r;  // output 0: t       [B,1,V]
        out[NB * NV + (size_t)b * NV + v] = r;  // output 1: outputs [B,O,V]
    }
}

extern "C" void kernel_launch(void* const* d_in, const int* in_sizes, int n_in,
                              void* d_out, int out_size, void* d_ws, size_t ws_size,
                              hipStream_t stream) {
    const float* x = (const float*)d_in[0];   // [32, 4096, 8]
    const float* W = (const float*)d_in[1];   // [1, 4096, 512, 8]
    float* out     = (float*)d_out;           // 2 x [32,1,512] concatenated

    __fp16* xh       = (__fp16*)d_ws;                         // 2 MB
    __fp16* xl       = xh + (size_t)NB * NK;                  // 2 MB
    __fp16* partialh = xl + (size_t)NB * NK;                  // 2 MB (f16, KB=64)

    x_prep<<<(NB * NK / 8) / 256, 256, 0, stream>>>(x, xh, xl);
    caps_mfma<<<KB * 16, 1024, 0, stream>>>(W, xh, xl, partialh);
    caps_finish<<<NB, 1024, 0, stream>>>(partialh, out);
}